// Round 4
// baseline (309.340 us; speedup 1.0000x reference)
//
#include <hip/hip_runtime.h>
#include <hip/hip_bf16.h>

// B=4, S=2048, C=1024 attention block, fp32 in/out.
// fp16 MFMA (16x16x32), fp32 accumulate.
// Projection: fused fp32->fp16 conversion — stages A-tiles directly from the
// fp32 inputs (global_load_lds, 32KB fp32 A + 16KB fp16 B = 48KB -> 3
// blocks/CU), converts in-register at fragment read. Kills the big input-cvt
// dispatch. Weights still pre-converted by a tiny cvt kernel.
// Scores/attn: proven 128x128 BK=128 2-phase kernel (r3). XCD block remap.

typedef _Float16 half8 __attribute__((ext_vector_type(8)));
typedef _Float16 half4 __attribute__((ext_vector_type(4)));
typedef float f32x4 __attribute__((ext_vector_type(4)));

#define AS1(p) ((const __attribute__((address_space(1))) void*)(p))
#define AS3(p) ((__attribute__((address_space(3))) void*)(p))
#define MFMA16(a, b, c) __builtin_amdgcn_mfma_f32_16x16x32_f16(a, b, c, 0, 0, 0)

// ---------------- fp32 -> fp16 convert, weights only (3 x 1M elems) ---------
__global__ __launch_bounds__(256) void cvtw_f32_f16(
    const float* __restrict__ wq, const float* __restrict__ wk,
    const float* __restrict__ wv, _Float16* __restrict__ Wqh) {
    constexpr long WSZ = 1048576;
    const int b = blockIdx.x;
    const int tz = b >> 9;
    const float* s = tz == 0 ? wq : tz == 1 ? wk : wv;
    _Float16* d = Wqh + (long)tz * WSZ;
    const long i = (long)(b & 511) * 2048 + threadIdx.x * 8;
    float4 a = *(const float4*)(s + i);
    float4 c = *(const float4*)(s + i + 4);
    half8 h;
    h[0] = (_Float16)a.x; h[1] = (_Float16)a.y; h[2] = (_Float16)a.z; h[3] = (_Float16)a.w;
    h[4] = (_Float16)c.x; h[5] = (_Float16)c.y; h[6] = (_Float16)c.z; h[7] = (_Float16)c.w;
    *(half8*)(d + i) = h;
}

// ---------------- fused projection: A fp32, B fp16, 128x128, BK=64 ----------
// C = X @ W^T + bias for Q,K,V in one dispatch; V writes Vt (transposed).
// A-tile staged fp32: 128 rows x 64 floats (256B row = 16 x 16B chunks),
// swizzle: logical chunk q of row r at physical q^(r&15); staging source
// pre-inverse-swizzled, LDS dest linear (slab s = 4 rows, lane -> (row
// lane>>4, phys chunk lane&15), dest byte = s*1024 + lane*16). Fragment read:
// half8 = 2 x f32x4 at phys chunks (2f)^l16, (2f+1)^l16 (f = ks*4+quad),
// converted in-register (RTN, numerics identical to separate cvt kernel).
// B-tile staged fp16 exactly as the proven r0 kernel (8-chunk XOR swizzle).
__global__ __launch_bounds__(256, 2)
void gemm_proj_a32(const float* __restrict__ X0, const float* __restrict__ X1,
                   const float* __restrict__ X2, const _Float16* __restrict__ Wh,
                   const float* __restrict__ b0, const float* __restrict__ b1,
                   const float* __restrict__ b2, _Float16* __restrict__ QKout,
                   _Float16* __restrict__ VtOut) {
    constexpr int K = 1024;
    __shared__ float AsmF[128 * 64] __attribute__((aligned(16)));   // 32 KB
    __shared__ _Float16 Bsm[128 * 64] __attribute__((aligned(16))); // 16 KB
    const int tid = threadIdx.x;
    const int lane = tid & 63;
    const int wave = tid >> 6;

    // grid: 1536 = 8 xcd * (R=24 row_ids) * 8 xt; row_id in 0..191
    const int lin = blockIdx.x;
    const int g = lin & 7;
    const int s = lin >> 3;
    const int xt = s & 7;
    const int row_id = g * 24 + (s >> 3);
    const int yt = row_id & 63;
    const int tz = row_id >> 6;          // 0,1,2 = Q,K,V
    const int m0 = yt * 128;
    const int n0 = xt * 128;

    const float* Xp = tz == 0 ? X0 : tz == 1 ? X1 : X2;
    const float* bias = tz == 0 ? b0 : tz == 1 ? b1 : b2;
    const float* Abase = Xp + (long)m0 * K;
    const _Float16* Bbase = Wh + (long)tz * 1048576 + (long)n0 * K;

    // A staging per-lane constants
    const int rin = lane >> 4;           // row within 4-row slab
    const int pch = lane & 15;           // physical 16B chunk
    // B staging per-lane constants
    const int srow8 = lane >> 3;
    const int sq = ((lane & 7) ^ srow8) << 3;
    // fragment per-lane constants
    const int quad = lane >> 4;
    const int l16 = lane & 15;
    const int wm = (wave >> 1) << 6;
    const int wn = (wave & 1) << 6;
    const int fa_base = (wm + l16) * 64;   // floats
    const int fb_base = (wn + l16) * 64;   // halves
    int chB[2];
#pragma unroll
    for (int ks = 0; ks < 2; ++ks) chB[ks] = ((ks * 4 + quad) ^ (l16 & 7)) << 3;
    int chA0[2], chA1[2];
#pragma unroll
    for (int ks = 0; ks < 2; ++ks) {
        const int f = ks * 4 + quad;
        chA0[ks] = ((2 * f) ^ l16) << 2;       // float offsets
        chA1[ks] = ((2 * f + 1) ^ l16) << 2;
    }

    f32x4 acc[4][4];
#pragma unroll
    for (int i = 0; i < 4; i++)
#pragma unroll
        for (int j = 0; j < 4; j++)
#pragma unroll
            for (int r = 0; r < 4; r++) acc[i][j][r] = 0.0f;

    for (int k0 = 0; k0 < K; k0 += 64) {
        __syncthreads();  // previous iteration's LDS reads complete
        // A: 32 slabs (4 rows x 64 floats = 1KB each), 8 insts/thread
#pragma unroll
        for (int u = 0; u < 8; ++u) {
            const int sl = wave + u * 4;             // 0..31
            const int r = sl * 4 + rin;              // row 0..127
            const int lq = (pch ^ (r & 15)) << 2;    // src float offset
            __builtin_amdgcn_global_load_lds(
                AS1(Abase + (long)r * K + k0 + lq),
                AS3(AsmF + sl * 256), 16, 0, 0);
        }
        // B: 16 slabs (8 rows x 64 halves = 1KB each), 4 insts/thread
#pragma unroll
        for (int u = 0; u < 4; ++u) {
            const int t = wave + u * 4;              // 0..15
            __builtin_amdgcn_global_load_lds(
                AS1(Bbase + (long)(t * 8 + srow8) * K + k0 + sq),
                AS3(Bsm + t * 512), 16, 0, 0);
        }
        __syncthreads();  // staging drained

#pragma unroll
        for (int ks = 0; ks < 2; ++ks) {
            half8 af[4], bf[4];
#pragma unroll
            for (int i = 0; i < 4; i++) {
                const f32x4 lo = *(const f32x4*)(AsmF + fa_base + i * 1024 + chA0[ks]);
                const f32x4 hi = *(const f32x4*)(AsmF + fa_base + i * 1024 + chA1[ks]);
                af[i][0] = (_Float16)lo[0]; af[i][1] = (_Float16)lo[1];
                af[i][2] = (_Float16)lo[2]; af[i][3] = (_Float16)lo[3];
                af[i][4] = (_Float16)hi[0]; af[i][5] = (_Float16)hi[1];
                af[i][6] = (_Float16)hi[2]; af[i][7] = (_Float16)hi[3];
            }
#pragma unroll
            for (int j = 0; j < 4; j++) bf[j] = *(const half8*)(Bsm + fb_base + j * 1024 + chB[ks]);
#pragma unroll
            for (int i = 0; i < 4; i++)
#pragma unroll
                for (int j = 0; j < 4; j++)
                    acc[i][j] = MFMA16(af[i], bf[j], acc[i][j]);
        }
    }

    // Epilogue: C/D layout col=lane&15, row=quad*4+reg.
    const bool trout = (tz == 2);
#pragma unroll
    for (int i = 0; i < 4; i++) {
        const int row = m0 + wm + i * 16 + quad * 4;
#pragma unroll
        for (int j = 0; j < 4; j++) {
            const int col = n0 + wn + j * 16 + l16;
            const float badd = bias[col];
            if (trout) {
                const long b = row >> 11;
                const int sl = row & 2047;
                half4 h;
#pragma unroll
                for (int r = 0; r < 4; r++) h[r] = (_Float16)(acc[i][j][r] + badd);
                *(half4*)(VtOut + b * 2097152 + (long)col * 2048 + sl) = h;
            } else {
                _Float16* o = QKout + (long)tz * 8388608;
#pragma unroll
                for (int r = 0; r < 4; r++)
                    o[(long)(row + r) * 1024 + col] = (_Float16)(acc[i][j][r] + badd);
            }
        }
    }
}

// ---------------- NT GEMM, 128x128 tile, BK=128 (scores + attn) -------------
// LDS rows = 128 halves (256 B = 16 x 16B chunks). Swizzle: logical chunk q
// of row r at physical q^(r&15). 64 slabs/iter (A:0-31, B:32-63).
template <int K, int NX_SH, int R, int NYT_SH, bool F16OUT>
__global__ __launch_bounds__(256, 2)
void gemm_nt(const _Float16* __restrict__ A, const _Float16* __restrict__ Bt,
             void* __restrict__ Cout, int N, float scale,
             long sA, long sB, long sC) {
    __shared__ _Float16 Asm[128 * 128] __attribute__((aligned(16)));
    __shared__ _Float16 Bsm[128 * 128] __attribute__((aligned(16)));
    const int tid = threadIdx.x;
    const int lane = tid & 63;
    const int wave = tid >> 6;

    const int lin = blockIdx.x;
    const int g = lin & 7;
    const int s = lin >> 3;
    const int xt = s & ((1 << NX_SH) - 1);
    const int row_id = g * R + (s >> NX_SH);
    const int yt = row_id & ((1 << NYT_SH) - 1);
    const int tz = row_id >> NYT_SH;     // batch id
    const int m0 = yt * 128;
    const int n0 = xt * 128;

    A += (long)tz * sA;
    Bt += (long)tz * sB;

    const int rin = lane >> 4;
    const int pch = lane & 15;
    const int quad = lane >> 4;
    const int l16 = lane & 15;
    const int wm = (wave >> 1) << 6;
    const int wn = (wave & 1) << 6;
    const int fa_base = (wm + l16) * 128;
    const int fb_base = (wn + l16) * 128;
    int ch[4];
#pragma unroll
    for (int ks = 0; ks < 4; ++ks) ch[ks] = (((ks * 4 + quad) ^ l16) << 3);

    f32x4 acc[4][4];
#pragma unroll
    for (int i = 0; i < 4; i++)
#pragma unroll
        for (int j = 0; j < 4; j++)
#pragma unroll
            for (int r = 0; r < 4; r++) acc[i][j][r] = 0.0f;

    const _Float16* Abase = A + (long)m0 * K;
    const _Float16* Bbase = Bt + (long)n0 * K;

    for (int k0 = 0; k0 < K; k0 += 128) {
        __syncthreads();
#pragma unroll
        for (int u = 0; u < 16; ++u) {
            const int t = wave + u * 4;            // slab 0..63
            const int sl = t & 31;
            const int r = sl * 4 + rin;            // row 0..127
            const int lq = (pch ^ (((sl & 3) << 2) + rin)) << 3;  // halves
            if (t < 32) {
                __builtin_amdgcn_global_load_lds(
                    AS1(Abase + (long)r * K + k0 + lq),
                    AS3(Asm + sl * 512), 16, 0, 0);
            } else {
                __builtin_amdgcn_global_load_lds(
                    AS1(Bbase + (long)r * K + k0 + lq),
                    AS3(Bsm + sl * 512), 16, 0, 0);
            }
        }
        __syncthreads();

#pragma unroll
        for (int ks = 0; ks < 4; ++ks) {
            half8 af[4], bf[4];
#pragma unroll
            for (int i = 0; i < 4; i++) af[i] = *(const half8*)(Asm + fa_base + i * 2048 + ch[ks]);
#pragma unroll
            for (int j = 0; j < 4; j++) bf[j] = *(const half8*)(Bsm + fb_base + j * 2048 + ch[ks]);
#pragma unroll
            for (int i = 0; i < 4; i++)
#pragma unroll
                for (int j = 0; j < 4; j++)
                    acc[i][j] = MFMA16(af[i], bf[j], acc[i][j]);
        }
    }

#pragma unroll
    for (int i = 0; i < 4; i++) {
        const int row = m0 + wm + i * 16 + quad * 4;
#pragma unroll
        for (int j = 0; j < 4; j++) {
            const int col = n0 + wn + j * 16 + l16;
#pragma unroll
            for (int r = 0; r < 4; r++) {
                float v = acc[i][j][r] * scale;
                if constexpr (F16OUT)
                    ((_Float16*)Cout + (long)tz * sC)[(long)(row + r) * N + col] = (_Float16)v;
                else
                    ((float*)Cout + (long)tz * sC)[(long)(row + r) * N + col] = v;
            }
        }
    }
}

// ---------------- row softmax: fp16 scores [8192][2048] -> fp16 probs --------
__global__ __launch_bounds__(256) void softmax_f16(const _Float16* __restrict__ S,
                                                   _Float16* __restrict__ P) {
    const long row = blockIdx.x;
    const int t = threadIdx.x;
    const int wave = t >> 6, lane = t & 63;
    half8 h = ((const half8*)(S + row * 2048))[t];
    float v[8];
#pragma unroll
    for (int j = 0; j < 8; j++) v[j] = (float)h[j];
    float m = v[0];
#pragma unroll
    for (int j = 1; j < 8; j++) m = fmaxf(m, v[j]);
#pragma unroll
    for (int off = 32; off > 0; off >>= 1) m = fmaxf(m, __shfl_xor(m, off, 64));
    __shared__ float redm[4], reds[4];
    if (lane == 0) redm[wave] = m;
    __syncthreads();
    m = fmaxf(fmaxf(redm[0], redm[1]), fmaxf(redm[2], redm[3]));
    float sum = 0.0f;
#pragma unroll
    for (int j = 0; j < 8; j++) { v[j] = __expf(v[j] - m); sum += v[j]; }
#pragma unroll
    for (int off = 32; off > 0; off >>= 1) sum += __shfl_xor(sum, off, 64);
    if (lane == 0) reds[wave] = sum;
    __syncthreads();
    sum = (reds[0] + reds[1]) + (reds[2] + reds[3]);
    const float inv = 1.0f / sum;
    half8 o;
#pragma unroll
    for (int j = 0; j < 8; j++) o[j] = (_Float16)(v[j] * inv);
    ((half8*)(P + row * 2048))[t] = o;
}

// ---------------- launch ----------------------------------------------------
extern "C" void kernel_launch(void* const* d_in, const int* in_sizes, int n_in,
                              void* d_out, int out_size, void* d_ws, size_t ws_size,
                              hipStream_t stream) {
    constexpr int B = 4, S = 2048, C = 1024;
    constexpr long XSZ = (long)B * S * C;   // 8388608

    const float* query = (const float*)d_in[0];
    const float* key   = (const float*)d_in[1];
    const float* value = (const float*)d_in[2];
    const float* Wq = (const float*)d_in[3];
    const float* bq = (const float*)d_in[4];
    const float* Wk = (const float*)d_in[5];
    const float* bk = (const float*)d_in[6];
    const float* Wv = (const float*)d_in[7];
    const float* bv = (const float*)d_in[8];
    float* out = (float*)d_out;
    char* ws = (char*)d_ws;

    // Workspace (bytes): [0,33554432) fp16 scores/probs region.
    // [50331648,56623104) Wqh,Wkh,Wvh contiguous. [73400320) Qh,Kh contiguous
    // (overwritten by attn probs after scores). [106954752) Vt.
    _Float16* Wqh = (_Float16*)(ws + 50331648);
    _Float16* scores = (_Float16*)(ws + 0);
    _Float16* Qh  = (_Float16*)(ws + 73400320);
    _Float16* attn = (_Float16*)(ws + 73400320);
    _Float16* Vt  = (_Float16*)(ws + 106954752);
    if (ws_size < 123731968) return;

    // 1) convert weights to fp16 (contiguous dest)
    cvtw_f32_f16<<<1536, 256, 0, stream>>>(Wq, Wk, Wv, Wqh);

    // 2) fused projections, A read directly as fp32: per tensor M=8192 (64 y),
    //    N=1024 (8 x). row_ids = 192, grid = 1536, R = 24.
    gemm_proj_a32<<<1536, 256, 0, stream>>>(
        query, key, value, Wqh, bq, bk, bv, Qh, Vt);

    // 3) scores = Qh @ Kh^T / 32, fp16 out. 16 x, 16 y, z=4 -> grid 1024, R=8.
    gemm_nt<1024, 4, 8, 4, true><<<1024, 256, 0, stream>>>(
        Qh, Qh + XSZ, scores, S, 0.03125f,
        (long)S * C, (long)S * C, (long)S * S);

    // 4) row softmax (fp16 in/out)
    softmax_f16<<<B * S, 256, 0, stream>>>(scores, attn);

    // 5) out = attn @ Vt^T. 8 x, 16 y, z=4 -> grid 512. fp32 out.
    gemm_nt<2048, 3, 8, 4, false><<<512, 256, 0, stream>>>(
        attn, Vt, out, C, 1.0f,
        (long)S * S, (long)C * S, (long)S * C);
}

// Round 5
// 299.657 us; speedup vs baseline: 1.0323x; 1.0323x over previous
//
#include <hip/hip_runtime.h>
#include <hip/hip_bf16.h>

// B=4, S=2048, C=1024 attention block, fp32 in/out.
// fp16 MFMA (16x16x32), fp32 accumulate. Best-of-measured composition:
//  - projection: r0 kernel (BK=64, 32KB LDS, 62.3us measured)
//  - scores/attn: r3 kernel (BK=128, 64KB LDS; fewer barrier drains at long K)
//  - cvt: single merged dispatch (r3)
//  - softmax: NEW 4-rows-per-block, one row per wave, no LDS/no barriers
// XOR-chunk LDS swizzles throughout (measured 0 bank conflicts).

typedef _Float16 half8 __attribute__((ext_vector_type(8)));
typedef _Float16 half4 __attribute__((ext_vector_type(4)));
typedef float f32x4 __attribute__((ext_vector_type(4)));

#define AS1(p) ((const __attribute__((address_space(1))) void*)(p))
#define AS3(p) ((__attribute__((address_space(3))) void*)(p))
#define MFMA16(a, b, c) __builtin_amdgcn_mfma_f32_16x16x32_f16(a, b, c, 0, 0, 0)

// ---------------- fp32 -> fp16 convert, 6 tensors, ONE launch ---------------
__global__ __launch_bounds__(256) void cvt6_f32_f16(
    const float* __restrict__ q, const float* __restrict__ k,
    const float* __restrict__ v, const float* __restrict__ wq,
    const float* __restrict__ wk, const float* __restrict__ wv,
    _Float16* __restrict__ Xq, _Float16* __restrict__ Wqh) {
    constexpr long XSZ = 8388608, WSZ = 1048576;
    const int b = blockIdx.x;
    const float* s;
    _Float16* d;
    long i;
    if (b < 12288) {
        const int tz = b >> 12;
        s = tz == 0 ? q : tz == 1 ? k : v;
        d = Xq + (long)tz * XSZ;
        i = (long)(b & 4095) * 2048 + threadIdx.x * 8;
    } else {
        const int b2 = b - 12288;
        const int tz = b2 >> 9;
        s = tz == 0 ? wq : tz == 1 ? wk : wv;
        d = Wqh + (long)tz * WSZ;
        i = (long)(b2 & 511) * 2048 + threadIdx.x * 8;
    }
    float4 a = *(const float4*)(s + i);
    float4 c = *(const float4*)(s + i + 4);
    half8 h;
    h[0] = (_Float16)a.x; h[1] = (_Float16)a.y; h[2] = (_Float16)a.z; h[3] = (_Float16)a.w;
    h[4] = (_Float16)c.x; h[5] = (_Float16)c.y; h[6] = (_Float16)c.z; h[7] = (_Float16)c.w;
    *(half8*)(d + i) = h;
}

// ---------------- projection GEMM, 128x128 tile, BK=64 (r0, 62.3us) ---------
// C[m,n] = sum_k A[m,k]*Bt[n,k] + bias[n], Q/K/V in one dispatch, V -> Vt.
// LDS rows = 64 halves (128B = 8 x 16B chunks); chunk q of row r at q^(r&7).
__global__ __launch_bounds__(256, 2)
void gemm_proj(const _Float16* __restrict__ A, const _Float16* __restrict__ Bt,
               const float* __restrict__ b0, const float* __restrict__ b1,
               const float* __restrict__ b2, _Float16* __restrict__ QKout,
               _Float16* __restrict__ VtOut) {
    constexpr int K = 1024;
    __shared__ _Float16 Asm[128 * 64] __attribute__((aligned(16)));
    __shared__ _Float16 Bsm[128 * 64] __attribute__((aligned(16)));
    const int tid = threadIdx.x;
    const int lane = tid & 63;
    const int wave = tid >> 6;

    // grid 1536 = 8 xcd * (R=24 row_ids) * 8 xt; row_id in 0..191
    const int lin = blockIdx.x;
    const int g = lin & 7;
    const int s = lin >> 3;
    const int xt = s & 7;
    const int row_id = g * 24 + (s >> 3);
    const int yt = row_id & 63;
    const int tz = row_id >> 6;          // 0,1,2 = Q,K,V
    const int m0 = yt * 128;
    const int n0 = xt * 128;

    const float* bias = tz == 0 ? b0 : tz == 1 ? b1 : b2;
    const _Float16* Abase = A + (long)tz * 8388608 + (long)m0 * K;
    const _Float16* Bbase = Bt + (long)tz * 1048576 + (long)n0 * K;

    const int srow8 = lane >> 3;
    const int sq = ((lane & 7) ^ srow8) << 3;
    const int quad = lane >> 4;
    const int l16 = lane & 15;
    const int wm = (wave >> 1) << 6;
    const int wn = (wave & 1) << 6;
    const int fa0 = (wm + l16) * 64 + (((0 * 4 + quad) ^ (l16 & 7)) << 3);
    const int fa1 = (wm + l16) * 64 + (((1 * 4 + quad) ^ (l16 & 7)) << 3);
    const int fb0 = (wn + l16) * 64 + (((0 * 4 + quad) ^ (l16 & 7)) << 3);
    const int fb1 = (wn + l16) * 64 + (((1 * 4 + quad) ^ (l16 & 7)) << 3);

    f32x4 acc[4][4];
#pragma unroll
    for (int i = 0; i < 4; i++)
#pragma unroll
        for (int j = 0; j < 4; j++)
#pragma unroll
            for (int r = 0; r < 4; r++) acc[i][j][r] = 0.0f;

    for (int k0 = 0; k0 < K; k0 += 64) {
        __syncthreads();
#pragma unroll
        for (int u = 0; u < 8; ++u) {
            const int t = wave + u * 4;  // slab 0..31 (A:0-15, B:16-31)
            if (t < 16) {
                __builtin_amdgcn_global_load_lds(
                    AS1(Abase + (long)(t * 8 + srow8) * K + k0 + sq),
                    AS3(Asm + t * 512), 16, 0, 0);
            } else {
                __builtin_amdgcn_global_load_lds(
                    AS1(Bbase + (long)((t - 16) * 8 + srow8) * K + k0 + sq),
                    AS3(Bsm + (t - 16) * 512), 16, 0, 0);
            }
        }
        __syncthreads();

#pragma unroll
        for (int ks = 0; ks < 2; ++ks) {
            const int ao = ks ? fa1 : fa0;
            const int bo = ks ? fb1 : fb0;
            half8 af[4], bf[4];
#pragma unroll
            for (int i = 0; i < 4; i++) af[i] = *(const half8*)(Asm + ao + i * 1024);
#pragma unroll
            for (int j = 0; j < 4; j++) bf[j] = *(const half8*)(Bsm + bo + j * 1024);
#pragma unroll
            for (int i = 0; i < 4; i++)
#pragma unroll
                for (int j = 0; j < 4; j++)
                    acc[i][j] = MFMA16(af[i], bf[j], acc[i][j]);
        }
    }

    // Epilogue: C/D layout col=lane&15, row=quad*4+reg.
    const bool trout = (tz == 2);
#pragma unroll
    for (int i = 0; i < 4; i++) {
        const int row = m0 + wm + i * 16 + quad * 4;
#pragma unroll
        for (int j = 0; j < 4; j++) {
            const int col = n0 + wn + j * 16 + l16;
            const float badd = bias[col];
            if (trout) {
                const long b = row >> 11;
                const int sl = row & 2047;
                half4 h;
#pragma unroll
                for (int r = 0; r < 4; r++) h[r] = (_Float16)(acc[i][j][r] + badd);
                *(half4*)(VtOut + b * 2097152 + (long)col * 2048 + sl) = h;
            } else {
                _Float16* o = QKout + (long)tz * 8388608;
#pragma unroll
                for (int r = 0; r < 4; r++)
                    o[(long)(row + r) * 1024 + col] = (_Float16)(acc[i][j][r] + badd);
            }
        }
    }
}

// ---------------- NT GEMM, 128x128 tile, BK=128 (scores + attn, r3) ---------
// LDS rows = 128 halves (256B = 16 x 16B chunks); chunk q of row r at q^(r&15).
template <int K, int NX_SH, int R, int NYT_SH, bool F16OUT>
__global__ __launch_bounds__(256, 2)
void gemm_nt(const _Float16* __restrict__ A, const _Float16* __restrict__ Bt,
             void* __restrict__ Cout, int N, float scale,
             long sA, long sB, long sC) {
    __shared__ _Float16 Asm[128 * 128] __attribute__((aligned(16)));
    __shared__ _Float16 Bsm[128 * 128] __attribute__((aligned(16)));
    const int tid = threadIdx.x;
    const int lane = tid & 63;
    const int wave = tid >> 6;

    const int lin = blockIdx.x;
    const int g = lin & 7;
    const int s = lin >> 3;
    const int xt = s & ((1 << NX_SH) - 1);
    const int row_id = g * R + (s >> NX_SH);
    const int yt = row_id & ((1 << NYT_SH) - 1);
    const int tz = row_id >> NYT_SH;     // batch id
    const int m0 = yt * 128;
    const int n0 = xt * 128;

    A += (long)tz * sA;
    Bt += (long)tz * sB;

    const int rin = lane >> 4;
    const int pch = lane & 15;
    const int quad = lane >> 4;
    const int l16 = lane & 15;
    const int wm = (wave >> 1) << 6;
    const int wn = (wave & 1) << 6;
    const int fa_base = (wm + l16) * 128;
    const int fb_base = (wn + l16) * 128;
    int ch[4];
#pragma unroll
    for (int ks = 0; ks < 4; ++ks) ch[ks] = (((ks * 4 + quad) ^ l16) << 3);

    f32x4 acc[4][4];
#pragma unroll
    for (int i = 0; i < 4; i++)
#pragma unroll
        for (int j = 0; j < 4; j++)
#pragma unroll
            for (int r = 0; r < 4; r++) acc[i][j][r] = 0.0f;

    const _Float16* Abase = A + (long)m0 * K;
    const _Float16* Bbase = Bt + (long)n0 * K;

    for (int k0 = 0; k0 < K; k0 += 128) {
        __syncthreads();
#pragma unroll
        for (int u = 0; u < 16; ++u) {
            const int t = wave + u * 4;            // slab 0..63 (A:0-31, B:32-63)
            const int sl = t & 31;
            const int r = sl * 4 + rin;            // row 0..127
            const int lq = (pch ^ (((sl & 3) << 2) + rin)) << 3;  // halves
            if (t < 32) {
                __builtin_amdgcn_global_load_lds(
                    AS1(Abase + (long)r * K + k0 + lq),
                    AS3(Asm + sl * 512), 16, 0, 0);
            } else {
                __builtin_amdgcn_global_load_lds(
                    AS1(Bbase + (long)r * K + k0 + lq),
                    AS3(Bsm + sl * 512), 16, 0, 0);
            }
        }
        __syncthreads();

#pragma unroll
        for (int ks = 0; ks < 4; ++ks) {
            half8 af[4], bf[4];
#pragma unroll
            for (int i = 0; i < 4; i++) af[i] = *(const half8*)(Asm + fa_base + i * 2048 + ch[ks]);
#pragma unroll
            for (int j = 0; j < 4; j++) bf[j] = *(const half8*)(Bsm + fb_base + j * 2048 + ch[ks]);
#pragma unroll
            for (int i = 0; i < 4; i++)
#pragma unroll
                for (int j = 0; j < 4; j++)
                    acc[i][j] = MFMA16(af[i], bf[j], acc[i][j]);
        }
    }

#pragma unroll
    for (int i = 0; i < 4; i++) {
        const int row = m0 + wm + i * 16 + quad * 4;
#pragma unroll
        for (int j = 0; j < 4; j++) {
            const int col = n0 + wn + j * 16 + l16;
#pragma unroll
            for (int r = 0; r < 4; r++) {
                float v = acc[i][j][r] * scale;
                if constexpr (F16OUT)
                    ((_Float16*)Cout + (long)tz * sC)[(long)(row + r) * N + col] = (_Float16)v;
                else
                    ((float*)Cout + (long)tz * sC)[(long)(row + r) * N + col] = v;
            }
        }
    }
}

// ---------------- row softmax: 4 rows/block, 1 row/wave, no barriers --------
// fp16 scores [8192][2048] -> fp16 probs. Per wave: 64 lanes x 4 half8 = one
// 2048-elem row; pure shuffle reduce (6 steps), no LDS, no __syncthreads.
__global__ __launch_bounds__(256) void softmax4_f16(const _Float16* __restrict__ S,
                                                    _Float16* __restrict__ P) {
    const int wave = threadIdx.x >> 6;
    const int lane = threadIdx.x & 63;
    const long row = (long)blockIdx.x * 4 + wave;
    const _Float16* src = S + row * 2048;
    _Float16* dst = P + row * 2048;

    half8 h[4];
#pragma unroll
    for (int u = 0; u < 4; u++) h[u] = ((const half8*)src)[lane + 64 * u];
    float v[32];
#pragma unroll
    for (int u = 0; u < 4; u++)
#pragma unroll
        for (int j = 0; j < 8; j++) v[u * 8 + j] = (float)h[u][j];

    float m = v[0];
#pragma unroll
    for (int e = 1; e < 32; e++) m = fmaxf(m, v[e]);
#pragma unroll
    for (int off = 32; off > 0; off >>= 1) m = fmaxf(m, __shfl_xor(m, off, 64));

    float sum = 0.0f;
#pragma unroll
    for (int e = 0; e < 32; e++) { v[e] = __expf(v[e] - m); sum += v[e]; }
#pragma unroll
    for (int off = 32; off > 0; off >>= 1) sum += __shfl_xor(sum, off, 64);
    const float inv = 1.0f / sum;

#pragma unroll
    for (int u = 0; u < 4; u++) {
        half8 o;
#pragma unroll
        for (int j = 0; j < 8; j++) o[j] = (_Float16)(v[u * 8 + j] * inv);
        ((half8*)dst)[lane + 64 * u] = o;
    }
}

// ---------------- launch ----------------------------------------------------
extern "C" void kernel_launch(void* const* d_in, const int* in_sizes, int n_in,
                              void* d_out, int out_size, void* d_ws, size_t ws_size,
                              hipStream_t stream) {
    constexpr int B = 4, S = 2048, C = 1024;
    constexpr long XSZ = (long)B * S * C;   // 8388608

    const float* query = (const float*)d_in[0];
    const float* key   = (const float*)d_in[1];
    const float* value = (const float*)d_in[2];
    const float* Wq = (const float*)d_in[3];
    const float* bq = (const float*)d_in[4];
    const float* Wk = (const float*)d_in[5];
    const float* bk = (const float*)d_in[6];
    const float* Wv = (const float*)d_in[7];
    const float* bv = (const float*)d_in[8];
    float* out = (float*)d_out;
    char* ws = (char*)d_ws;

    // Workspace (bytes): [0,50331648) Xq,Xk,Xv fp16 contiguous; region reused
    // for fp16 scores after the projection. [50331648,56623104) Wqh,Wkh,Wvh.
    // [73400320) Qh,Kh contiguous (reused for attn probs). [106954752) Vt.
    _Float16* Xq  = (_Float16*)(ws + 0);
    _Float16* Wqh = (_Float16*)(ws + 3 * XSZ * 2);
    _Float16* scores = (_Float16*)(ws + 0);
    _Float16* Qh  = (_Float16*)(ws + 73400320);
    _Float16* attn = (_Float16*)(ws + 73400320);
    _Float16* Vt  = (_Float16*)(ws + 106954752);
    if (ws_size < 123731968) return;

    // 1) convert inputs + weights to fp16 (one launch, contiguous dests)
    cvt6_f32_f16<<<13824, 256, 0, stream>>>(
        query, key, value, Wq, Wk, Wv, Xq, Wqh);

    // 2) merged projections (BK=64, r0 kernel): per tensor M=8192 (64 y),
    //    N=1024 (8 x), K=1024. row_ids = 192, grid = 1536, R = 24.
    gemm_proj<<<1536, 256, 0, stream>>>(
        Xq, Wqh, bq, bk, bv, Qh, Vt);

    // 3) scores = Qh @ Kh^T / 32, fp16 out (BK=128). 16 x, 16 y, z=4 ->
    //    grid 1024, R=8.
    gemm_nt<1024, 4, 8, 4, true><<<1024, 256, 0, stream>>>(
        Qh, Qh + XSZ, scores, S, 0.03125f,
        (long)S * C, (long)S * C, (long)S * S);

    // 4) row softmax (fp16 in/out), 4 rows/block, no barriers
    softmax4_f16<<<B * S / 4, 256, 0, stream>>>(scores, attn);

    // 5) out = attn @ Vt^T (BK=128). 8 x, 16 y, z=4 -> grid 512. fp32 out.
    gemm_nt<2048, 3, 8, 4, false><<<512, 256, 0, stream>>>(
        attn, Vt, out, C, 1.0f,
        (long)S * S, (long)C * S, (long)S * C);
}